// Round 7
// baseline (1393.046 us; speedup 1.0000x reference)
//
#include <hip/hip_runtime.h>
#include <hip/hip_cooperative_groups.h>
#include <stdint.h>
#include <limits.h>

// Problem constants (fixed by the reference file)
#define BB 4
#define NI 64
#define CC 16
#define KK 4
#define HH 480
#define WW 480
#define PLANE (HH * WW)      // 230400 pixels per (b,c) plane
#define NG (PLANE / 4)       // 57600 groups-of-4-pixels per plane
#define TPB 256
#define BIGV (1 << 30)
#define NPLANE (BB * CC)     // 64

// Fused (cooperative) decomposition
#define NSEG 15              // segments (blocks) per plane
#define GPB 3840             // groups per block
#define GPT 15               // groups per thread
#define NBLK (NPLANE * NSEG) // 960 blocks

// Fallback (3-kernel) decomposition
#define BPP 45               // blocks per plane
#define GPT3 5               // groups per thread

// Native vector types (required by __builtin_nontemporal_*)
typedef float v4f __attribute__((ext_vector_type(4)));
typedef int   v4i __attribute__((ext_vector_type(4)));

// Workspace layout (shared by both paths; disjoint regions):
//   [0, SEL8_BYTES)  : packed byte per pixel (fallback path only)
//   ints after that  : partials[plane][*][8] + mapping
#define SEL8_BYTES ((size_t)NPLANE * PLANE)
#define PART_STRIDE 8
#define MAP_OFF (NPLANE * BPP * PART_STRIDE)

__device__ __forceinline__ void coh_store(int* p, int v) {
    __hip_atomic_store(p, v, __ATOMIC_RELEASE, __HIP_MEMORY_SCOPE_AGENT);
}
__device__ __forceinline__ int coh_load(const int* p) {
    return __hip_atomic_load(p, __ATOMIC_ACQUIRE, __HIP_MEMORY_SCOPE_AGENT);
}

__device__ __forceinline__ int wred_min(int v) {
    for (int o = 32; o; o >>= 1) v = min(v, __shfl_down(v, o, 64));
    return v;
}
__device__ __forceinline__ int wred_max(int v) {
    for (int o = 32; o; o >>= 1) v = max(v, __shfl_down(v, o, 64));
    return v;
}
__device__ __forceinline__ int wred_or(int v) {
    for (int o = 32; o; o >>= 1) v |= __shfl_down(v, o, 64);
    return v;
}

// Shared device helper: per-env mapping construction from reduced stats.
__device__ __forceinline__ void build_mapping(
    const int* __restrict__ inst_ids, int b, int max_id,
    const int (*s_ov)[4], const int* s_pr, int ci_want, int* map_out) {
    for (int ci = 0; ci < CC; ci++) {
        int base2 = (b * CC + ci) * KK;
        int id[KK], ov[KK], prb[KK];
        int prbits = s_pr[ci];
        for (int t = 0; t < KK; t++) {
            id[t] = inst_ids[base2 + t];
            ov[t] = s_ov[ci][t];
            prb[t] = (prbits >> t) & 1;
        }
        int ord[KK] = {0, 1, 2, 3};
        for (int i = 1; i < KK; i++) {       // insertion sort by id
            int key = ord[i], j = i - 1;
            while (j >= 0 && id[ord[j]] > id[key]) { ord[j + 1] = ord[j]; j--; }
            ord[j + 1] = key;
        }
        int map_slot[KK];
        int prev_id = -1, cur_map = 0, cnt_new = 0;
        for (int j = 0; j < KK; j++) {
            int s = ord[j], l = id[s];
            if (l != prev_id) {
                int cov = INT_MAX, cpr = 0;
                for (int t = 0; t < KK; t++)
                    if (id[t] == l) { cov = min(cov, ov[t]); cpr |= prb[t]; }
                if (l == 0) cur_map = 0;
                else {
                    bool has = cov < BIGV;
                    bool isnew = cpr && !has;
                    if (isnew) { cnt_new++; cur_map = max_id + cnt_new; }
                    else cur_map = has ? cov : 0;
                }
                prev_id = l;
            }
            map_slot[s] = cur_map;
        }
        if (ci == ci_want)
            for (int t = 0; t < KK; t++) map_out[t] = map_slot[t];
        max_id += cnt_new;
    }
}

// ============================ Fused cooperative path ============================
__global__ __launch_bounds__(TPB, 4) void fused_kernel(
    const float* __restrict__ update, const int* __restrict__ initmap,
    const int* __restrict__ inst_ids, int* __restrict__ out, int* wsi) {
    namespace cg = cooperative_groups;
    cg::grid_group grid = cg::this_grid();

    __shared__ unsigned int s_packed[GPB];   // 15 KB packed bytes p = s*50+g
    __shared__ int red[4][6];
    __shared__ int s_ov[CC][4];
    __shared__ int s_pr[CC];
    __shared__ int s_gm[CC];
    __shared__ int s_map[4];

    int blk = blockIdx.x;
    int plane = blk / NSEG;
    int seg = blk % NSEG;
    int b = plane >> 4;
    int ci_own = plane & 15;
    int tid = threadIdx.x;

    int idbase = plane * KK;
    int id0 = inst_ids[idbase + 0], id1 = inst_ids[idbase + 1];
    int id2 = inst_ids[idbase + 2], id3 = inst_ids[idbase + 3];

    const v4f* u0 = (const v4f*)(update + ((size_t)b * NI + id0) * PLANE);
    const v4f* u1 = (const v4f*)(update + ((size_t)b * NI + id1) * PLANE);
    const v4f* u2 = (const v4f*)(update + ((size_t)b * NI + id2) * PLANE);
    const v4f* u3 = (const v4f*)(update + ((size_t)b * NI + id3) * PLANE);
    const v4i* gl = (const v4i*)(initmap + (size_t)plane * PLANE);

    int lmin0 = INT_MAX, lmin1 = INT_MAX, lmin2 = INT_MAX, lmin3 = INT_MAX;
    int pres = 0, gmax = 0;
    int gbase = seg * GPB;

#pragma unroll
    for (int it = 0; it < GPT; it++) {
        int g = gbase + it * TPB + tid;
        v4f a  = __builtin_nontemporal_load(&u0[g]);
        v4f b2 = __builtin_nontemporal_load(&u1[g]);
        v4f c  = __builtin_nontemporal_load(&u2[g]);
        v4f d  = __builtin_nontemporal_load(&u3[g]);
        v4i gv = __builtin_nontemporal_load(&gl[g]);

        unsigned int packed = 0;
#pragma unroll
        for (int e = 0; e < 4; e++) {
            float best = 1e-5f; int s = 0;
            if (a[e]  > best) { best = a[e];  s = 1; }
            if (b2[e] > best) { best = b2[e]; s = 2; }
            if (c[e]  > best) { best = c[e];  s = 3; }
            if (d[e]  > best) { s = 4; }
            int gve = gv[e];
            packed |= (unsigned int)(s * 50 + gve) << (8 * e);
            gmax = max(gmax, gve);
            if (s) {
                int kk = s - 1; pres |= 1 << kk;
                int v = gve ? gve : BIGV;
                if (kk == 0) lmin0 = min(lmin0, v);
                else if (kk == 1) lmin1 = min(lmin1, v);
                else if (kk == 2) lmin2 = min(lmin2, v);
                else lmin3 = min(lmin3, v);
            }
        }
        s_packed[it * TPB + tid] = packed;
    }

    lmin0 = wred_min(lmin0); lmin1 = wred_min(lmin1);
    lmin2 = wred_min(lmin2); lmin3 = wred_min(lmin3);
    pres = wred_or(pres); gmax = wred_max(gmax);

    int wv = tid >> 6, lane = tid & 63;
    if (lane == 0) {
        red[wv][0] = lmin0; red[wv][1] = lmin1; red[wv][2] = lmin2;
        red[wv][3] = lmin3; red[wv][4] = pres;  red[wv][5] = gmax;
    }
    __syncthreads();
    if (tid == 0) {
        int m0 = red[0][0], m1 = red[0][1], m2 = red[0][2], m3 = red[0][3];
        int pr = red[0][4], gm = red[0][5];
        for (int w2 = 1; w2 < 4; w2++) {
            m0 = min(m0, red[w2][0]); m1 = min(m1, red[w2][1]);
            m2 = min(m2, red[w2][2]); m3 = min(m3, red[w2][3]);
            pr |= red[w2][4]; gm = max(gm, red[w2][5]);
        }
        int* pp = wsi + ((size_t)plane * NSEG + seg) * PART_STRIDE;
        coh_store(&pp[0], m0); coh_store(&pp[1], m1);
        coh_store(&pp[2], m2); coh_store(&pp[3], m3);
        coh_store(&pp[4], pr); coh_store(&pp[5], gm);
    }

    __threadfence();
    grid.sync();

    if (tid < CC) {
        int pl = b * CC + tid;
        int m0 = INT_MAX, m1 = INT_MAX, m2 = INT_MAX, m3 = INT_MAX, pr = 0, gm = 0;
        for (int s = 0; s < NSEG; s++) {
            const int* pp = wsi + ((size_t)pl * NSEG + s) * PART_STRIDE;
            m0 = min(m0, coh_load(&pp[0]));
            m1 = min(m1, coh_load(&pp[1]));
            m2 = min(m2, coh_load(&pp[2]));
            m3 = min(m3, coh_load(&pp[3]));
            pr |= coh_load(&pp[4]);
            gm = max(gm, coh_load(&pp[5]));
        }
        s_ov[tid][0] = m0; s_ov[tid][1] = m1;
        s_ov[tid][2] = m2; s_ov[tid][3] = m3;
        s_pr[tid] = pr; s_gm[tid] = gm;
    }
    __syncthreads();
    if (tid == 0) {
        int max_id = 0;
        for (int ci = 0; ci < CC; ci++) max_id = max(max_id, s_gm[ci]);
        build_mapping(inst_ids, b, max_id, s_ov, s_pr, ci_own, s_map);
    }
    __syncthreads();

    int m0 = s_map[0], m1 = s_map[1], m2 = s_map[2], m3 = s_map[3];
    v4i* op = (v4i*)(out + (size_t)plane * PLANE);
#pragma unroll
    for (int it = 0; it < GPT; it++) {
        int g = gbase + it * TPB + tid;
        unsigned int u = s_packed[it * TPB + tid];
        v4i ov;
#pragma unroll
        for (int e = 0; e < 4; e++) {
            unsigned int p = (u >> (8 * e)) & 0xFFu;
            int s = (int)((p * 41u) >> 11);      // exact p/50 for p in [0,249]
            int gvv = (int)p - s * 50;
            int mv = (s == 1) ? m0 : (s == 2) ? m1 : (s == 3) ? m2 : m3;
            ov[e] = s ? max(gvv, mv) : gvv;
        }
        __builtin_nontemporal_store(ov, &op[g]);
    }
}

// ============================ Fallback 3-kernel path ============================
__global__ __launch_bounds__(TPB) void stats_kernel(
    const float* __restrict__ update, const int* __restrict__ initmap,
    const int* __restrict__ inst_ids, unsigned int* __restrict__ sel8,
    int* __restrict__ wsi) {
    int plane = blockIdx.x / BPP;
    int chunk = blockIdx.x % BPP;
    int b = plane >> 4;

    int idbase = plane * KK;
    int id0 = inst_ids[idbase + 0], id1 = inst_ids[idbase + 1];
    int id2 = inst_ids[idbase + 2], id3 = inst_ids[idbase + 3];

    const v4f* u0 = (const v4f*)(update + ((size_t)b * NI + id0) * PLANE);
    const v4f* u1 = (const v4f*)(update + ((size_t)b * NI + id1) * PLANE);
    const v4f* u2 = (const v4f*)(update + ((size_t)b * NI + id2) * PLANE);
    const v4f* u3 = (const v4f*)(update + ((size_t)b * NI + id3) * PLANE);
    const v4i* gl = (const v4i*)(initmap + (size_t)plane * PLANE);
    unsigned int* sp = sel8 + (size_t)plane * NG;

    int lmin0 = INT_MAX, lmin1 = INT_MAX, lmin2 = INT_MAX, lmin3 = INT_MAX;
    int pres = 0, gmax = 0;

    int base = chunk * (TPB * GPT3);
#pragma unroll
    for (int it = 0; it < GPT3; it++) {
        int g = base + it * TPB + threadIdx.x;
        v4f a  = __builtin_nontemporal_load(&u0[g]);
        v4f b2 = __builtin_nontemporal_load(&u1[g]);
        v4f c  = __builtin_nontemporal_load(&u2[g]);
        v4f d  = __builtin_nontemporal_load(&u3[g]);
        v4i gv = __builtin_nontemporal_load(&gl[g]);

        unsigned int packed = 0;
#pragma unroll
        for (int e = 0; e < 4; e++) {
            float best = 1e-5f; int s = 0;
            if (a[e]  > best) { best = a[e];  s = 1; }
            if (b2[e] > best) { best = b2[e]; s = 2; }
            if (c[e]  > best) { best = c[e];  s = 3; }
            if (d[e]  > best) { s = 4; }
            int gve = gv[e];
            packed |= (unsigned int)(s * 50 + gve) << (8 * e);
            gmax = max(gmax, gve);
            if (s) {
                int kk = s - 1; pres |= 1 << kk;
                int v = gve ? gve : BIGV;
                if (kk == 0) lmin0 = min(lmin0, v);
                else if (kk == 1) lmin1 = min(lmin1, v);
                else if (kk == 2) lmin2 = min(lmin2, v);
                else lmin3 = min(lmin3, v);
            }
        }
        sp[g] = packed;
    }

    lmin0 = wred_min(lmin0); lmin1 = wred_min(lmin1);
    lmin2 = wred_min(lmin2); lmin3 = wred_min(lmin3);
    pres = wred_or(pres); gmax = wred_max(gmax);

    __shared__ int red[4][6];
    int wv = threadIdx.x >> 6, lane = threadIdx.x & 63;
    if (lane == 0) {
        red[wv][0] = lmin0; red[wv][1] = lmin1; red[wv][2] = lmin2;
        red[wv][3] = lmin3; red[wv][4] = pres;  red[wv][5] = gmax;
    }
    __syncthreads();
    if (threadIdx.x == 0) {
        int m0 = red[0][0], m1 = red[0][1], m2 = red[0][2], m3 = red[0][3];
        int pr = red[0][4], gm = red[0][5];
        for (int w2 = 1; w2 < 4; w2++) {
            m0 = min(m0, red[w2][0]); m1 = min(m1, red[w2][1]);
            m2 = min(m2, red[w2][2]); m3 = min(m3, red[w2][3]);
            pr |= red[w2][4]; gm = max(gm, red[w2][5]);
        }
        int* pp = wsi + ((size_t)plane * BPP + chunk) * PART_STRIDE;
        pp[0] = m0; pp[1] = m1; pp[2] = m2; pp[3] = m3; pp[4] = pr; pp[5] = gm;
    }
}

__global__ void mapping_kernel(const int* __restrict__ inst_ids, int* wsi) {
    __shared__ int s_ov[NPLANE][4];
    __shared__ int s_pr[NPLANE];
    __shared__ int s_gm[NPLANE];

    int plane = threadIdx.x;
    int m0 = INT_MAX, m1 = INT_MAX, m2 = INT_MAX, m3 = INT_MAX, pr = 0, gm = 0;
    for (int ch = 0; ch < BPP; ch++) {
        const int* pp = wsi + ((size_t)plane * BPP + ch) * PART_STRIDE;
        m0 = min(m0, pp[0]); m1 = min(m1, pp[1]);
        m2 = min(m2, pp[2]); m3 = min(m3, pp[3]);
        pr |= pp[4]; gm = max(gm, pp[5]);
    }
    s_ov[plane][0] = m0; s_ov[plane][1] = m1;
    s_ov[plane][2] = m2; s_ov[plane][3] = m3;
    s_pr[plane] = pr; s_gm[plane] = gm;
    __syncthreads();

    if (threadIdx.x < BB) {
        int b = threadIdx.x;
        int max_id = 0;
        for (int ci = 0; ci < CC; ci++) max_id = max(max_id, s_gm[b * CC + ci]);
        for (int ci = 0; ci < CC; ci++) {
            int mp[4];
            build_mapping(inst_ids, b, max_id, &s_ov[b * CC], &s_pr[b * CC], ci, mp);
            // build_mapping recomputes cnt_new internally per call; emulate running max_id:
            // simpler: recompute full chain each ci with same max_id is WRONG — so instead
            // inline original loop below.
            (void)mp;
        }
        // original sequential loop (correct running max_id):
        for (int ci = 0; ci < CC; ci++) {
            int base2 = (b * CC + ci) * KK;
            int id[KK], ov[KK], prb[KK];
            int prbits = s_pr[b * CC + ci];
            for (int t = 0; t < KK; t++) {
                id[t] = inst_ids[base2 + t];
                ov[t] = s_ov[b * CC + ci][t];
                prb[t] = (prbits >> t) & 1;
            }
            int ord[KK] = {0, 1, 2, 3};
            for (int i = 1; i < KK; i++) {
                int key = ord[i], j = i - 1;
                while (j >= 0 && id[ord[j]] > id[key]) { ord[j + 1] = ord[j]; j--; }
                ord[j + 1] = key;
            }
            int map_slot[KK];
            int prev_id = -1, cur_map = 0, cnt_new = 0;
            for (int j = 0; j < KK; j++) {
                int s = ord[j], l = id[s];
                if (l != prev_id) {
                    int cov = INT_MAX, cpr = 0;
                    for (int t = 0; t < KK; t++)
                        if (id[t] == l) { cov = min(cov, ov[t]); cpr |= prb[t]; }
                    if (l == 0) cur_map = 0;
                    else {
                        bool has = cov < BIGV;
                        bool isnew = cpr && !has;
                        if (isnew) { cnt_new++; cur_map = max_id + cnt_new; }
                        else cur_map = has ? cov : 0;
                    }
                    prev_id = l;
                }
                map_slot[s] = cur_map;
            }
            for (int t = 0; t < KK; t++) wsi[MAP_OFF + base2 + t] = map_slot[t];
            max_id += cnt_new;
        }
    }
}

__global__ __launch_bounds__(TPB) void remap_kernel(
    const unsigned int* __restrict__ sel8, const int* __restrict__ wsi,
    int* __restrict__ out) {
    int plane = blockIdx.x / BPP;
    int chunk = blockIdx.x % BPP;

    int m0 = wsi[MAP_OFF + plane * 4 + 0];
    int m1 = wsi[MAP_OFF + plane * 4 + 1];
    int m2 = wsi[MAP_OFF + plane * 4 + 2];
    int m3 = wsi[MAP_OFF + plane * 4 + 3];

    const unsigned int* sp = sel8 + (size_t)plane * NG;
    v4i* op = (v4i*)(out + (size_t)plane * PLANE);

    int base = chunk * (TPB * GPT3);
#pragma unroll
    for (int it = 0; it < GPT3; it++) {
        int g = base + it * TPB + threadIdx.x;
        unsigned int u = sp[g];
        v4i ov;
#pragma unroll
        for (int e = 0; e < 4; e++) {
            unsigned int p = (u >> (8 * e)) & 0xFFu;
            int s = (int)((p * 41u) >> 11);
            int gvv = (int)p - s * 50;
            int mv = (s == 1) ? m0 : (s == 2) ? m1 : (s == 3) ? m2 : m3;
            ov[e] = s ? max(gvv, mv) : gvv;
        }
        __builtin_nontemporal_store(ov, &op[g]);
    }
}

extern "C" void kernel_launch(void* const* d_in, const int* in_sizes, int n_in,
                              void* d_out, int out_size, void* d_ws, size_t ws_size,
                              hipStream_t stream) {
    const float* update = (const float*)d_in[0];
    const int* initmap = (const int*)d_in[1];
    const int* inst_ids = (const int*)d_in[2];
    int* out = (int*)d_out;

    unsigned int* sel8 = (unsigned int*)d_ws;
    int* wsi = (int*)((uint8_t*)d_ws + SEL8_BYTES);

    void* args[] = {(void*)&update, (void*)&initmap, (void*)&inst_ids,
                    (void*)&out, (void*)&wsi};
    hipError_t err = hipLaunchCooperativeKernel((const void*)fused_kernel,
                                                dim3(NBLK), dim3(TPB), args, 0, stream);
    if (err != hipSuccess) {
        (void)hipGetLastError();   // clear sticky error, run proven 3-kernel path
        stats_kernel<<<NPLANE * BPP, TPB, 0, stream>>>(update, initmap, inst_ids, sel8, wsi);
        mapping_kernel<<<1, NPLANE, 0, stream>>>(inst_ids, wsi);
        remap_kernel<<<NPLANE * BPP, TPB, 0, stream>>>(sel8, wsi, out);
    }
}